// Round 1
// baseline (2041.200 us; speedup 1.0000x reference)
//
#include <hip/hip_runtime.h>

// ---- problem constants ----
#define N_IMG 512      // B*C = 8*64
#define C_CH  64
#define H_IN  512
#define W_IN  512
#define NC    259      // subband extent: (512+8-1)//2
#define PIT   260      // padded row pitch (floats), 16B-aligned
#define S_IMG (NC*PIT) // per-image per-subband floats = 67340
#define SB    ((size_t)N_IMG * S_IMG)
#define GP    260      // gate pitch

// sym4-style filters (from reference DEC_LO)
constexpr float DLO[8] = {
  -0.010597401784997278f,  0.032883011666982945f,  0.030841381835986965f, -0.18703481171888114f,
  -0.02798376941698385f,   0.6308807679295904f,    0.7148465705525415f,    0.23037781330885523f};
// DEC_HI[m] = (m odd ? + : -) * DEC_LO[7-m]
constexpr float DHI[8] = {
  -0.23037781330885523f,   0.7148465705525415f,   -0.6308807679295904f,   -0.02798376941698385f,
   0.18703481171888114f,   0.030841381835986965f, -0.032883011666982945f, -0.010597401784997278f};
// REC_LO[m] = DEC_LO[7-m]
constexpr float RLO[8] = {
   0.23037781330885523f,   0.7148465705525415f,    0.6308807679295904f,   -0.02798376941698385f,
  -0.18703481171888114f,   0.030841381835986965f,  0.032883011666982945f, -0.010597401784997278f};
// REC_HI[m] = (m even ? + : -) * DEC_LO[m]
constexpr float RHI[8] = {
  -0.010597401784997278f, -0.032883011666982945f,  0.030841381835986965f,  0.18703481171888114f,
  -0.02798376941698385f,  -0.6308807679295904f,    0.7148465705525415f,   -0.23037781330885523f};

// =====================================================================
// Kernel 1: fused row DWT + column DWT. Each block: one (bc, strip of 8
// subband rows). Stages 22 row-DWT'd rows (a,d) in LDS, then does the
// column DWT producing LL/LH/HL/HH rows.
// =====================================================================
__global__ __launch_bounds__(256) void k_fwd(const float* __restrict__ x,
                                             float* __restrict__ ws) {
  __shared__ float sa[22][PIT];
  __shared__ float sd[22][PIT];
  const int bc = blockIdx.y;
  const int h0 = blockIdx.x * 8;
  const int hcount = min(8, NC - h0);
  const int nrows = 2 * hcount + 6;       // x-row positions 2h0-6 .. 2(h0+hcount-1)+1
  const int tid = threadIdx.x;
  const float* xim = x + (size_t)bc * (H_IN * (size_t)W_IN);

  // Phase A: row DWT of the needed x rows into LDS
  for (int j = 0; j < nrows; ++j) {
    int r = 2 * h0 - 6 + j;
    r = r < 0 ? -r - 1 : (r >= H_IN ? 2 * H_IN - 1 - r : r);   // symmetric reflect
    const float* xrow = xim + (size_t)r * W_IN;
    for (int i = tid; i < NC; i += 256) {
      float A = 0.f, D = 0.f;
      if (i >= 3 && i <= 255) {
#pragma unroll
        for (int m = 0; m < 8; ++m) {
          float v = xrow[2 * i + 1 - m];
          A += DLO[m] * v; D += DHI[m] * v;
        }
      } else {
#pragma unroll
        for (int m = 0; m < 8; ++m) {
          int p = 2 * i + 1 - m;
          p = p < 0 ? -p - 1 : (p >= W_IN ? 2 * W_IN - 1 - p : p);
          float v = xrow[p];
          A += DLO[m] * v; D += DHI[m] * v;
        }
      }
      sa[j][i] = A; sd[j][i] = D;
    }
  }
  __syncthreads();

  // Phase B: column DWT -> 4 subbands
  for (int dh = 0; dh < hcount; ++dh) {
    const size_t ob = (size_t)bc * S_IMG + (size_t)(h0 + dh) * PIT;
    for (int i = tid; i < NC; i += 256) {
      float ll = 0.f, lh = 0.f, hl = 0.f, hh = 0.f;
#pragma unroll
      for (int m = 0; m < 8; ++m) {
        int j = 2 * dh + 7 - m;            // LDS row for x-row 2h+1-m
        float av = sa[j][i], dv = sd[j][i];
        ll += DLO[m] * av; lh += DHI[m] * av;
        hl += DLO[m] * dv; hh += DHI[m] * dv;
      }
      ws[         ob + i] = ll;
      ws[SB     + ob + i] = lh;
      ws[2 * SB + ob + i] = hl;
      ws[3 * SB + ob + i] = hh;
    }
  }
}

// =====================================================================
// Kernel 2: gates. One block per (b,c) image. LH: row-wise max/mean over
// w (wave-parallel). HL: column-wise max/mean over h (thread-per-column).
// Then 1x1 conv(2->1) + depthwise conv3 (zero pad) + BN(eval) + sigmoid.
// =====================================================================
__global__ __launch_bounds__(256) void k_gate(
    const float* __restrict__ ws, float* __restrict__ gout,
    const float* lc1w, const float* lc1b, const float* lc2w,
    const float* lg, const float* lb, const float* lm, const float* lv,
    const float* hc1w, const float* hc1b, const float* hc2w,
    const float* hg, const float* hb, const float* hm, const float* hv) {
  __shared__ float rmx[NC], rsm[NC], cmx[NC], csm[NC], y0a[NC], y0b[NC];
  const int bc = blockIdx.x;
  const int tid = threadIdx.x;
  const float* LH = ws +     SB + (size_t)bc * S_IMG;
  const float* HL = ws + 2 * SB + (size_t)bc * S_IMG;

  // LH row stats (pool over w)
  const int wave = tid >> 6, lane = tid & 63;
  for (int h = wave; h < NC; h += 4) {
    const float* row = LH + (size_t)h * PIT;
    float mx = -3.4e38f, sm = 0.f;
    for (int w = lane; w < NC; w += 64) { float v = row[w]; mx = fmaxf(mx, v); sm += v; }
#pragma unroll
    for (int off = 32; off; off >>= 1) {
      mx = fmaxf(mx, __shfl_xor(mx, off));
      sm += __shfl_xor(sm, off);
    }
    if (lane == 0) { rmx[h] = mx; rsm[h] = sm; }
  }
  // HL column stats (pool over h)
  float m0 = -3.4e38f, s0 = 0.f, m1 = -3.4e38f, s1 = 0.f;
  for (int h = 0; h < NC; ++h) {
    const float* row = HL + (size_t)h * PIT;
    float v = row[tid];
    m0 = fmaxf(m0, v); s0 += v;
    if (tid < NC - 256) { float v2 = row[256 + tid]; m1 = fmaxf(m1, v2); s1 += v2; }
  }
  cmx[tid] = m0; csm[tid] = s0;
  if (tid < NC - 256) { cmx[256 + tid] = m1; csm[256 + tid] = s1; }
  __syncthreads();

  const float lw0 = lc1w[0], lw1 = lc1w[1], lbb0 = lc1b[0];
  const float hw0 = hc1w[0], hw1 = hc1w[1], hbb0 = hc1b[0];
  for (int idx = tid; idx < NC; idx += 256) {
    y0a[idx] = lw0 * rmx[idx] + lw1 * (rsm[idx] * (1.f / NC)) + lbb0;
    y0b[idx] = hw0 * cmx[idx] + hw1 * (csm[idx] * (1.f / NC)) + hbb0;
  }
  __syncthreads();

  const int c = bc & (C_CH - 1);
  const float lk0 = lc2w[c * 3], lk1 = lc2w[c * 3 + 1], lk2 = lc2w[c * 3 + 2];
  const float hk0 = hc2w[c * 3], hk1 = hc2w[c * 3 + 1], hk2 = hc2w[c * 3 + 2];
  const float lsc = rsqrtf(lv[c] + 1e-5f) * lg[c], lmu = lm[c], lbe = lb[c];
  const float hsc = rsqrtf(hv[c] + 1e-5f) * hg[c], hmu = hm[c], hbe = hb[c];
  for (int idx = tid; idx < NC; idx += 256) {
    float a = idx > 0 ? y0a[idx - 1] : 0.f;
    float b = y0a[idx];
    float d = idx < NC - 1 ? y0a[idx + 1] : 0.f;
    float y = lk0 * a + lk1 * b + lk2 * d;
    y = (y - lmu) * lsc + lbe;
    gout[(size_t)bc * GP + idx] = 1.f / (1.f + expf(-y));

    a = idx > 0 ? y0b[idx - 1] : 0.f;
    b = y0b[idx];
    d = idx < NC - 1 ? y0b[idx + 1] : 0.f;
    y = hk0 * a + hk1 * b + hk2 * d;
    y = (y - hmu) * hsc + hbe;
    gout[(size_t)N_IMG * GP + (size_t)bc * GP + idx] = 1.f / (1.f + expf(-y));
  }
}

// =====================================================================
// Kernel 3: fused gating + column IDWT + row IDWT + residual add.
// Each block: one (bc, strip of 8 output rows). No boundary handling
// needed in the inverse (indices always interior).
// =====================================================================
__global__ __launch_bounds__(256) void k_inv(const float* __restrict__ ws,
                                             const float* __restrict__ x,
                                             float* __restrict__ out) {
  __shared__ float sA[7][PIT], sB[7][PIT], sC[7][PIT], sD[7][PIT];
  __shared__ float a2[8][PIT], d2[8][PIT];
  const int bc = blockIdx.y;
  const int t0 = blockIdx.x * 8;       // output row strip
  const int u0 = t0 >> 1;              // first needed subband row (u0..u0+6, <=258)
  const int tid = threadIdx.x;
  const float* LL = ws            + (size_t)bc * S_IMG;
  const float* LH = ws +     SB   + (size_t)bc * S_IMG;
  const float* HL = ws + 2 * SB   + (size_t)bc * S_IMG;
  const float* HH = ws + 3 * SB   + (size_t)bc * S_IMG;
  const float* glh = ws + 4 * SB + (size_t)bc * GP;
  const float* ghl = ws + 4 * SB + (size_t)N_IMG * GP + (size_t)bc * GP;

  // stage 7 subband rows, applying gates
  for (int j = 0; j < 7; ++j) {
    const int u = u0 + j;
    const float gl = glh[u];
    const size_t rb = (size_t)u * PIT;
    for (int i = tid; i < NC; i += 256) {
      sA[j][i] = LL[rb + i];
      sB[j][i] = LH[rb + i] * gl;       // LHp
      sC[j][i] = HL[rb + i] * ghl[i];   // HLp
      sD[j][i] = HH[rb + i];
    }
  }
  __syncthreads();

  // column IDWT -> a2, d2 (8 rows x 259 coeffs)
  for (int dt = 0; dt < 8; ++dt) {
    const int par = dt & 1;             // t0 even
    const int lj0 = dt >> 1;
    for (int i = tid; i < NC; i += 256) {
      float av = 0.f, dv = 0.f;
#pragma unroll
      for (int jj = 0; jj < 4; ++jj) {
        const int lj = lj0 + 3 - jj;
        const float rl = RLO[par + 2 * jj], rh = RHI[par + 2 * jj];
        av += sA[lj][i] * rl + sB[lj][i] * rh;
        dv += sC[lj][i] * rl + sD[lj][i] * rh;
      }
      a2[dt][i] = av; d2[dt][i] = dv;
    }
  }
  __syncthreads();

  // row IDWT + residual
  for (int dt = 0; dt < 8; ++dt) {
    const size_t orow = ((size_t)bc * H_IN + (size_t)(t0 + dt)) * W_IN;
    for (int s = tid; s < W_IN; s += 256) {
      const int q = s >> 1, par = s & 1;
      float v = 0.f;
#pragma unroll
      for (int jj = 0; jj < 4; ++jj) {
        const int qq = q + 3 - jj;
        v += a2[dt][qq] * RLO[par + 2 * jj] + d2[dt][qq] * RHI[par + 2 * jj];
      }
      out[orow + s] = x[orow + s] + v;
    }
  }
}

extern "C" void kernel_launch(void* const* d_in, const int* in_sizes, int n_in,
                              void* d_out, int out_size, void* d_ws, size_t ws_size,
                              hipStream_t stream) {
  const float* x = (const float*)d_in[0];
  float* ws = (float*)d_ws;
  float* out = (float*)d_out;

  // ws layout (floats): [LL | LH | HL | HH] each SB, then g_lh (512*260), g_hl (512*260)
  k_fwd<<<dim3(33, N_IMG), 256, 0, stream>>>(x, ws);
  k_gate<<<dim3(N_IMG), 256, 0, stream>>>(
      ws, ws + 4 * SB,
      (const float*)d_in[1], (const float*)d_in[2], (const float*)d_in[3],
      (const float*)d_in[4], (const float*)d_in[5], (const float*)d_in[6], (const float*)d_in[7],
      (const float*)d_in[8], (const float*)d_in[9], (const float*)d_in[10],
      (const float*)d_in[11], (const float*)d_in[12], (const float*)d_in[13], (const float*)d_in[14]);
  k_inv<<<dim3(64, N_IMG), 256, 0, stream>>>(ws, x, out);
}

// Round 2
// 1026.730 us; speedup vs baseline: 1.9881x; 1.9881x over previous
//
#include <hip/hip_runtime.h>

// ---- problem constants ----
#define N_IMG 512      // B*C = 8*64
#define C_CH  64
#define H_IN  512
#define W_IN  512
#define NC    259      // subband extent: (512+8-1)//2
#define PIT   260      // padded row pitch (floats), 16B-aligned
#define S_IMG (NC*PIT) // per-image per-subband floats = 67340
#define SB    ((size_t)N_IMG * S_IMG)
#define GP    260      // gate pitch

constexpr float DLO[8] = {
  -0.010597401784997278f,  0.032883011666982945f,  0.030841381835986965f, -0.18703481171888114f,
  -0.02798376941698385f,   0.6308807679295904f,    0.7148465705525415f,    0.23037781330885523f};
constexpr float DHI[8] = {
  -0.23037781330885523f,   0.7148465705525415f,   -0.6308807679295904f,   -0.02798376941698385f,
   0.18703481171888114f,   0.030841381835986965f, -0.032883011666982945f, -0.010597401784997278f};
constexpr float RLO[8] = {
   0.23037781330885523f,   0.7148465705525415f,    0.6308807679295904f,   -0.02798376941698385f,
  -0.18703481171888114f,   0.030841381835986965f,  0.032883011666982945f, -0.010597401784997278f};
constexpr float RHI[8] = {
  -0.010597401784997278f, -0.032883011666982945f,  0.030841381835986965f,  0.18703481171888114f,
  -0.02798376941698385f,  -0.6308807679295904f,    0.7148465705525415f,   -0.23037781330885523f};

// =====================================================================
// Kernel 1: fused row DWT + column DWT. 512 threads; two halves process
// alternating rows. Interior columns use coalesced float2 loads.
// =====================================================================
__global__ __launch_bounds__(512) void k_fwd(const float* __restrict__ x,
                                             float* __restrict__ ws) {
  __shared__ float sa[22 * PIT];
  __shared__ float sd[22 * PIT];
  const int bc = blockIdx.y;
  const int h0 = blockIdx.x * 8;
  const int hcount = min(8, NC - h0);
  const int nrows = 2 * hcount + 6;
  const int tid = threadIdx.x;
  const int half = tid >> 8, it = tid & 255;
  const float* xim = x + (size_t)bc * (H_IN * (size_t)W_IN);

  // Phase A: row DWT of needed x rows into LDS (halves alternate rows)
  for (int j = half; j < nrows; j += 2) {
    int r = 2 * h0 - 6 + j;
    r = r < 0 ? -r - 1 : (r >= H_IN ? 2 * H_IN - 1 - r : r);
    const float* xrow = xim + (size_t)r * W_IN;
    float* saj = sa + j * PIT;
    float* sdj = sd + j * PIT;
    for (int i = it; i < NC; i += 256) {
      float A, D;
      if (i >= 3 && i <= 255) {
        const float2 v0 = *(const float2*)(xrow + 2 * i - 6);
        const float2 v1 = *(const float2*)(xrow + 2 * i - 4);
        const float2 v2 = *(const float2*)(xrow + 2 * i - 2);
        const float2 v3 = *(const float2*)(xrow + 2 * i);
        A = DLO[7] * v0.x + DLO[6] * v0.y + DLO[5] * v1.x + DLO[4] * v1.y
          + DLO[3] * v2.x + DLO[2] * v2.y + DLO[1] * v3.x + DLO[0] * v3.y;
        D = DHI[7] * v0.x + DHI[6] * v0.y + DHI[5] * v1.x + DHI[4] * v1.y
          + DHI[3] * v2.x + DHI[2] * v2.y + DHI[1] * v3.x + DHI[0] * v3.y;
      } else {
        A = 0.f; D = 0.f;
#pragma unroll
        for (int m = 0; m < 8; ++m) {
          int p = 2 * i + 1 - m;
          p = p < 0 ? -p - 1 : (p >= W_IN ? 2 * W_IN - 1 - p : p);
          const float v = xrow[p];
          A += DLO[m] * v; D += DHI[m] * v;
        }
      }
      saj[i] = A; sdj[i] = D;
    }
  }
  __syncthreads();

  // Phase B: column DWT -> 4 subbands (halves alternate output rows)
  for (int dh = half; dh < hcount; dh += 2) {
    const size_t ob = (size_t)bc * S_IMG + (size_t)(h0 + dh) * PIT;
    for (int i = it; i < NC; i += 256) {
      float ll = 0.f, lh = 0.f, hl = 0.f, hh = 0.f;
#pragma unroll
      for (int m = 0; m < 8; ++m) {
        const int j = 2 * dh + 7 - m;
        const float av = sa[j * PIT + i], dv = sd[j * PIT + i];
        ll += DLO[m] * av; lh += DHI[m] * av;
        hl += DLO[m] * dv; hh += DHI[m] * dv;
      }
      ws[         ob + i] = ll;
      ws[SB     + ob + i] = lh;
      ws[2 * SB + ob + i] = hl;
      ws[3 * SB + ob + i] = hh;
    }
  }
}

// =====================================================================
// Kernel 2: gates. 512 threads: waves 0-3 do LH row stats, waves 4-7 do
// HL column stats concurrently. Then conv/BN/sigmoid epilogue.
// =====================================================================
__global__ __launch_bounds__(512) void k_gate(
    const float* __restrict__ ws, float* __restrict__ gout,
    const float* lc1w, const float* lc1b, const float* lc2w,
    const float* lg, const float* lb, const float* lm, const float* lv,
    const float* hc1w, const float* hc1b, const float* hc2w,
    const float* hg, const float* hb, const float* hm, const float* hv) {
  __shared__ float rmx[NC], rsm[NC], cmx[NC], csm[NC], y0a[NC], y0b[NC];
  const int bc = blockIdx.x;
  const int tid = threadIdx.x;
  const float* LH = ws +     SB + (size_t)bc * S_IMG;
  const float* HL = ws + 2 * SB + (size_t)bc * S_IMG;
  const int wave = tid >> 6, lane = tid & 63;

  if (wave < 4) {
    // LH row stats (pool over w), one row per wave
    for (int h = wave; h < NC; h += 4) {
      const float* row = LH + (size_t)h * PIT;
      float mx = -3.4e38f, sm = 0.f;
      for (int w = lane; w < NC; w += 64) { float v = row[w]; mx = fmaxf(mx, v); sm += v; }
#pragma unroll
      for (int off = 32; off; off >>= 1) {
        mx = fmaxf(mx, __shfl_xor(mx, off));
        sm += __shfl_xor(sm, off);
      }
      if (lane == 0) { rmx[h] = mx; rsm[h] = sm; }
    }
  } else {
    // HL column stats (pool over h), one column per thread
    const int c0 = tid - 256;
    float m0 = -3.4e38f, s0 = 0.f, m1 = -3.4e38f, s1 = 0.f;
    for (int h = 0; h < NC; ++h) {
      const float* row = HL + (size_t)h * PIT;
      const float v = row[c0];
      m0 = fmaxf(m0, v); s0 += v;
      if (c0 < NC - 256) { const float v2 = row[256 + c0]; m1 = fmaxf(m1, v2); s1 += v2; }
    }
    cmx[c0] = m0; csm[c0] = s0;
    if (c0 < NC - 256) { cmx[256 + c0] = m1; csm[256 + c0] = s1; }
  }
  __syncthreads();

  const float lw0 = lc1w[0], lw1 = lc1w[1], lbb0 = lc1b[0];
  const float hw0 = hc1w[0], hw1 = hc1w[1], hbb0 = hc1b[0];
  for (int idx = tid; idx < NC; idx += 512) {
    y0a[idx] = lw0 * rmx[idx] + lw1 * (rsm[idx] * (1.f / NC)) + lbb0;
    y0b[idx] = hw0 * cmx[idx] + hw1 * (csm[idx] * (1.f / NC)) + hbb0;
  }
  __syncthreads();

  const int c = bc & (C_CH - 1);
  const float lk0 = lc2w[c * 3], lk1 = lc2w[c * 3 + 1], lk2 = lc2w[c * 3 + 2];
  const float hk0 = hc2w[c * 3], hk1 = hc2w[c * 3 + 1], hk2 = hc2w[c * 3 + 2];
  const float lsc = rsqrtf(lv[c] + 1e-5f) * lg[c], lmu = lm[c], lbe = lb[c];
  const float hsc = rsqrtf(hv[c] + 1e-5f) * hg[c], hmu = hm[c], hbe = hb[c];
  for (int idx = tid; idx < NC; idx += 512) {
    float a = idx > 0 ? y0a[idx - 1] : 0.f;
    float b = y0a[idx];
    float d = idx < NC - 1 ? y0a[idx + 1] : 0.f;
    float y = lk0 * a + lk1 * b + lk2 * d;
    y = (y - lmu) * lsc + lbe;
    gout[(size_t)bc * GP + idx] = 1.f / (1.f + expf(-y));

    a = idx > 0 ? y0b[idx - 1] : 0.f;
    b = y0b[idx];
    d = idx < NC - 1 ? y0b[idx + 1] : 0.f;
    y = hk0 * a + hk1 * b + hk2 * d;
    y = (y - hmu) * hsc + hbe;
    gout[(size_t)N_IMG * GP + (size_t)bc * GP + idx] = 1.f / (1.f + expf(-y));
  }
}

// =====================================================================
// Kernel 3: gating + column IDWT + row IDWT + residual. 512 threads,
// float4 staging, ghl gate folded into the column IDWT, float2 output.
// =====================================================================
__global__ __launch_bounds__(512) void k_inv(const float* __restrict__ ws,
                                             const float* __restrict__ x,
                                             float* __restrict__ out) {
  __shared__ float sA[7][PIT], sB[7][PIT], sC[7][PIT], sD[7][PIT];
  __shared__ float a2[8][PIT], d2[8][PIT];
  __shared__ float sghl[PIT];
  const int bc = blockIdx.y;
  const int t0 = blockIdx.x * 8;       // output row strip (always full 8)
  const int u0 = t0 >> 1;              // subband rows u0..u0+6 (<= 258)
  const int tid = threadIdx.x;
  const int half = tid >> 8, it = tid & 255;
  const float* LL = ws            + (size_t)bc * S_IMG;
  const float* LH = ws +     SB   + (size_t)bc * S_IMG;
  const float* HL = ws + 2 * SB   + (size_t)bc * S_IMG;
  const float* HH = ws + 3 * SB   + (size_t)bc * S_IMG;
  const float* glh = ws + 4 * SB + (size_t)bc * GP;
  const float* ghl = ws + 4 * SB + (size_t)N_IMG * GP + (size_t)bc * GP;

  if (tid < 65) *(float4*)(sghl + 4 * tid) = *(const float4*)(ghl + 4 * tid);

  // stage 7 rows x 4 subbands as float4 (65 quads cover cols 0..259)
  for (int q = tid; q < 7 * 65; q += 512) {
    const int j = q / 65, i4 = (q - j * 65) * 4;
    const int u = u0 + j;
    const float gl = glh[u];
    const size_t rb = (size_t)u * PIT + i4;
    float4 vA = *(const float4*)(LL + rb);
    float4 vB = *(const float4*)(LH + rb);
    const float4 vC = *(const float4*)(HL + rb);
    const float4 vD = *(const float4*)(HH + rb);
    *(float4*)(&sA[j][i4]) = vA;
    vB.x *= gl; vB.y *= gl; vB.z *= gl; vB.w *= gl;
    *(float4*)(&sB[j][i4]) = vB;
    *(float4*)(&sC[j][i4]) = vC;
    *(float4*)(&sD[j][i4]) = vD;
  }
  __syncthreads();

  // column IDWT -> a2, d2 (ghl gate factored out of the HL sum)
  for (int d = 0; d < 4; ++d) {
    const int dt = 2 * d + half;
    const int par = dt & 1, lj0 = dt >> 1;
    for (int i = it; i < NC; i += 256) {
      float av = 0.f, dvl = 0.f, dvh = 0.f;
#pragma unroll
      for (int jj = 0; jj < 4; ++jj) {
        const int lj = lj0 + 3 - jj;
        const float rl = RLO[par + 2 * jj], rh = RHI[par + 2 * jj];
        av  += sA[lj][i] * rl + sB[lj][i] * rh;
        dvl += sC[lj][i] * rl;
        dvh += sD[lj][i] * rh;
      }
      a2[dt][i] = av;
      d2[dt][i] = sghl[i] * dvl + dvh;
    }
  }
  __syncthreads();

  // row IDWT + residual; each thread produces a float2 (cols 2q, 2q+1)
  for (int d = 0; d < 4; ++d) {
    const int dt = 2 * d + half;
    const size_t orow = ((size_t)bc * H_IN + (size_t)(t0 + dt)) * W_IN;
    const int q = it;                    // 256 pairs exactly
    const float a0v = a2[dt][q], a1v = a2[dt][q + 1], a2v = a2[dt][q + 2], a3v = a2[dt][q + 3];
    const float d0v = d2[dt][q], d1v = d2[dt][q + 1], d2v = d2[dt][q + 2], d3v = d2[dt][q + 3];
    const float v0 = a3v * RLO[0] + d3v * RHI[0] + a2v * RLO[2] + d2v * RHI[2]
                   + a1v * RLO[4] + d1v * RHI[4] + a0v * RLO[6] + d0v * RHI[6];
    const float v1 = a3v * RLO[1] + d3v * RHI[1] + a2v * RLO[3] + d2v * RHI[3]
                   + a1v * RLO[5] + d1v * RHI[5] + a0v * RLO[7] + d0v * RHI[7];
    const float2 xv = *(const float2*)(x + orow + 2 * q);
    float2 ov; ov.x = xv.x + v0; ov.y = xv.y + v1;
    *(float2*)(out + orow + 2 * q) = ov;
  }
}

extern "C" void kernel_launch(void* const* d_in, const int* in_sizes, int n_in,
                              void* d_out, int out_size, void* d_ws, size_t ws_size,
                              hipStream_t stream) {
  const float* x = (const float*)d_in[0];
  float* ws = (float*)d_ws;
  float* out = (float*)d_out;

  k_fwd<<<dim3(33, N_IMG), 512, 0, stream>>>(x, ws);
  k_gate<<<dim3(N_IMG), 512, 0, stream>>>(
      ws, ws + 4 * SB,
      (const float*)d_in[1], (const float*)d_in[2], (const float*)d_in[3],
      (const float*)d_in[4], (const float*)d_in[5], (const float*)d_in[6], (const float*)d_in[7],
      (const float*)d_in[8], (const float*)d_in[9], (const float*)d_in[10],
      (const float*)d_in[11], (const float*)d_in[12], (const float*)d_in[13], (const float*)d_in[14]);
  k_inv<<<dim3(64, N_IMG), 512, 0, stream>>>(ws, x, out);
}

// Round 3
// 649.589 us; speedup vs baseline: 3.1423x; 1.5806x over previous
//
#include <hip/hip_runtime.h>

typedef _Float16 h16;
typedef _Float16 h16x2 __attribute__((ext_vector_type(2)));
typedef _Float16 h16x4 __attribute__((ext_vector_type(4)));
typedef _Float16 h16x8 __attribute__((ext_vector_type(8)));

// ---- problem constants ----
#define N_IMG 512      // B*C = 8*64
#define C_CH  64
#define H_IN  512
#define W_IN  512
#define NC    259      // subband extent: (512+8-1)//2
#define PIT   260      // f32 LDS pitch (k_fwd)
#define PITH  264      // fp16 subband row pitch (rows 16B-aligned)
#define S_IMGH ((size_t)NC * PITH)          // 68376 halves per image per subband
#define NSB    ((size_t)N_IMG * S_IMGH)     // halves per subband
#define GPIT  264      // gate pitch (f32)

constexpr float DLO[8] = {
  -0.010597401784997278f,  0.032883011666982945f,  0.030841381835986965f, -0.18703481171888114f,
  -0.02798376941698385f,   0.6308807679295904f,    0.7148465705525415f,    0.23037781330885523f};
constexpr float DHI[8] = {
  -0.23037781330885523f,   0.7148465705525415f,   -0.6308807679295904f,   -0.02798376941698385f,
   0.18703481171888114f,   0.030841381835986965f, -0.032883011666982945f, -0.010597401784997278f};
constexpr float RLO[8] = {
   0.23037781330885523f,   0.7148465705525415f,    0.6308807679295904f,   -0.02798376941698385f,
  -0.18703481171888114f,   0.030841381835986965f,  0.032883011666982945f, -0.010597401784997278f};
constexpr float RHI[8] = {
  -0.010597401784997278f, -0.032883011666982945f,  0.030841381835986965f,  0.18703481171888114f,
  -0.02798376941698385f,  -0.6308807679295904f,    0.7148465705525415f,   -0.23037781330885523f};

__device__ __forceinline__ void dwt_scalar_reflect(const float* xrow, int i,
                                                   float& A, float& D) {
  A = 0.f; D = 0.f;
#pragma unroll
  for (int m = 0; m < 8; ++m) {
    int p = 2 * i + 1 - m;
    p = p < 0 ? -p - 1 : (p >= W_IN ? 2 * W_IN - 1 - p : p);
    const float v = xrow[p];
    A += DLO[m] * v; D += DHI[m] * v;
  }
}

// =====================================================================
// Kernel 1: fused row DWT + column DWT -> fp16 subbands.
// Phase A: each lane computes 4 outputs from 4 aligned float4 loads.
// Phase B: 4-col groups, float4 LDS reads, h16x4 (8B) stores.
// =====================================================================
__global__ __launch_bounds__(512) void k_fwd(const float* __restrict__ x,
                                             h16* __restrict__ wsh) {
  __shared__ float sa[22 * PIT];
  __shared__ float sd[22 * PIT];
  const int bc = blockIdx.y;
  const int h0 = blockIdx.x * 8;
  const int hcount = min(8, NC - h0);
  const int nrows = 2 * hcount + 6;
  const int tid = threadIdx.x;
  const int wave = tid >> 6, lane = tid & 63;
  const float* xim = x + (size_t)bc * (H_IN * (size_t)W_IN);

  // Phase A: row DWT of needed x rows into LDS
  for (int j = wave; j < nrows; j += 8) {
    int r = 2 * h0 - 6 + j;
    r = r < 0 ? -r - 1 : (r >= H_IN ? 2 * H_IN - 1 - r : r);
    const float* xrow = xim + (size_t)r * W_IN;
    float* saj = sa + j * PIT;
    float* sdj = sd + j * PIT;
    if (lane > 0) {
      // interior group g=lane: cols 4g..4g+3, taps 8g-6..8g+7 in [8g-8,8g+8)
      const int g = lane;
      const float* bp = xrow + 8 * g - 8;
      const float4 q0 = *(const float4*)(bp);
      const float4 q1 = *(const float4*)(bp + 4);
      const float4 q2 = *(const float4*)(bp + 8);
      const float4 q3 = *(const float4*)(bp + 12);
      const float v[16] = {q0.x, q0.y, q0.z, q0.w, q1.x, q1.y, q1.z, q1.w,
                           q2.x, q2.y, q2.z, q2.w, q3.x, q3.y, q3.z, q3.w};
      float A[4], D[4];
#pragma unroll
      for (int k = 0; k < 4; ++k) {
        float a = 0.f, d = 0.f;
#pragma unroll
        for (int m = 0; m < 8; ++m) {
          const float t = v[2 * k + 9 - m];
          a += DLO[m] * t; d += DHI[m] * t;
        }
        A[k] = a; D[k] = d;
      }
      *(float4*)(saj + 4 * g) = {A[0], A[1], A[2], A[3]};
      *(float4*)(sdj + 4 * g) = {D[0], D[1], D[2], D[3]};
      if (g <= 3) {                       // tail cols 256..258 on lanes 1..3
        const int i = 255 + g;
        float A2, D2; dwt_scalar_reflect(xrow, i, A2, D2);
        saj[i] = A2; sdj[i] = D2;
      }
    } else {                              // lane 0: boundary cols 0..3
#pragma unroll
      for (int i = 0; i < 4; ++i) {
        float A2, D2; dwt_scalar_reflect(xrow, i, A2, D2);
        saj[i] = A2; sdj[i] = D2;
      }
    }
  }
  __syncthreads();

  // Phase B: column DWT -> 4 fp16 subbands
  h16* __restrict__ LLp = wsh;
  h16* __restrict__ LHp = wsh + NSB;
  h16* __restrict__ HLp = wsh + 2 * NSB;
  h16* __restrict__ HHp = wsh + 3 * NSB;
  const size_t obase = (size_t)bc * S_IMGH;
  for (int task = tid; task < hcount * 65; task += 512) {
    const int dh = task / 65;
    const int p = task - dh * 65;
    const int i0 = 4 * p;
    float ll[4] = {0,0,0,0}, lh[4] = {0,0,0,0}, hl[4] = {0,0,0,0}, hh[4] = {0,0,0,0};
#pragma unroll
    for (int m = 0; m < 8; ++m) {
      const int j = 2 * dh + 7 - m;
      const float4 av = *(const float4*)(sa + j * PIT + i0);
      const float4 dv = *(const float4*)(sd + j * PIT + i0);
      const float favL = DLO[m], favH = DHI[m];
      ll[0] += favL * av.x; ll[1] += favL * av.y; ll[2] += favL * av.z; ll[3] += favL * av.w;
      lh[0] += favH * av.x; lh[1] += favH * av.y; lh[2] += favH * av.z; lh[3] += favH * av.w;
      hl[0] += favL * dv.x; hl[1] += favL * dv.y; hl[2] += favL * dv.z; hl[3] += favL * dv.w;
      hh[0] += favH * dv.x; hh[1] += favH * dv.y; hh[2] += favH * dv.z; hh[3] += favH * dv.w;
    }
    if (i0 == 256) { ll[3] = 0.f; lh[3] = 0.f; hl[3] = 0.f; hh[3] = 0.f; }  // col 259 pad = 0
    const size_t ob = obase + (size_t)(h0 + dh) * PITH + i0;
    h16x4 o;
    o[0] = (h16)ll[0]; o[1] = (h16)ll[1]; o[2] = (h16)ll[2]; o[3] = (h16)ll[3];
    *(h16x4*)(LLp + ob) = o;
    o[0] = (h16)lh[0]; o[1] = (h16)lh[1]; o[2] = (h16)lh[2]; o[3] = (h16)lh[3];
    *(h16x4*)(LHp + ob) = o;
    o[0] = (h16)hl[0]; o[1] = (h16)hl[1]; o[2] = (h16)hl[2]; o[3] = (h16)hl[3];
    *(h16x4*)(HLp + ob) = o;
    o[0] = (h16)hh[0]; o[1] = (h16)hh[1]; o[2] = (h16)hh[2]; o[3] = (h16)hh[3];
    *(h16x4*)(HHp + ob) = o;
  }
}

// =====================================================================
// Kernel 2: gates from fp16 subbands. Waves 0-3: LH row stats; waves
// 4-7: HL column stats (half2 per thread). Then conv/BN/sigmoid.
// =====================================================================
__global__ __launch_bounds__(512) void k_gate(
    const h16* __restrict__ wsh, float* __restrict__ gout,
    const float* lc1w, const float* lc1b, const float* lc2w,
    const float* lg, const float* lb, const float* lm, const float* lv,
    const float* hc1w, const float* hc1b, const float* hc2w,
    const float* hg, const float* hb, const float* hm, const float* hv) {
  __shared__ float rmx[NC], rsm[NC], cmx[NC], csm[NC], y0a[NC], y0b[NC];
  const int bc = blockIdx.x;
  const int tid = threadIdx.x;
  const h16* LHh = wsh +     NSB + (size_t)bc * S_IMGH;
  const h16* HLh = wsh + 2 * NSB + (size_t)bc * S_IMGH;
  const int wave = tid >> 6, lane = tid & 63;

  if (wave < 4) {
    for (int h = wave; h < NC; h += 4) {
      const h16* row = LHh + (size_t)h * PITH;
      float mx = -3.4e38f, sm = 0.f;
      for (int w2 = lane; w2 < 129; w2 += 64) {
        const h16x2 v = *(const h16x2*)(row + 2 * w2);
        const float vx = (float)v[0], vy = (float)v[1];
        mx = fmaxf(mx, fmaxf(vx, vy)); sm += vx + vy;
      }
      if (lane == 0) { const float t = (float)row[258]; mx = fmaxf(mx, t); sm += t; }
#pragma unroll
      for (int off = 32; off; off >>= 1) {
        mx = fmaxf(mx, __shfl_xor(mx, off));
        sm += __shfl_xor(sm, off);
      }
      if (lane == 0) { rmx[h] = mx; rsm[h] = sm; }
    }
  } else {
    const int t = tid - 256;
    if (t < 130) {
      float m0 = -3.4e38f, s0 = 0.f, m1 = -3.4e38f, s1 = 0.f;
      for (int h = 0; h < NC; ++h) {
        const h16x2 v = *(const h16x2*)(HLh + (size_t)h * PITH + 2 * t);
        const float vx = (float)v[0], vy = (float)v[1];
        m0 = fmaxf(m0, vx); s0 += vx;
        m1 = fmaxf(m1, vy); s1 += vy;
      }
      cmx[2 * t] = m0; csm[2 * t] = s0;
      if (2 * t + 1 < NC) { cmx[2 * t + 1] = m1; csm[2 * t + 1] = s1; }
    }
  }
  __syncthreads();

  const float lw0 = lc1w[0], lw1 = lc1w[1], lbb0 = lc1b[0];
  const float hw0 = hc1w[0], hw1 = hc1w[1], hbb0 = hc1b[0];
  for (int idx = tid; idx < NC; idx += 512) {
    y0a[idx] = lw0 * rmx[idx] + lw1 * (rsm[idx] * (1.f / NC)) + lbb0;
    y0b[idx] = hw0 * cmx[idx] + hw1 * (csm[idx] * (1.f / NC)) + hbb0;
  }
  __syncthreads();

  const int c = bc & (C_CH - 1);
  const float lk0 = lc2w[c * 3], lk1 = lc2w[c * 3 + 1], lk2 = lc2w[c * 3 + 2];
  const float hk0 = hc2w[c * 3], hk1 = hc2w[c * 3 + 1], hk2 = hc2w[c * 3 + 2];
  const float lsc = rsqrtf(lv[c] + 1e-5f) * lg[c], lmu = lm[c], lbe = lb[c];
  const float hsc = rsqrtf(hv[c] + 1e-5f) * hg[c], hmu = hm[c], hbe = hb[c];
  for (int idx = tid; idx < NC; idx += 512) {
    float a = idx > 0 ? y0a[idx - 1] : 0.f;
    float b = y0a[idx];
    float d = idx < NC - 1 ? y0a[idx + 1] : 0.f;
    float y = lk0 * a + lk1 * b + lk2 * d;
    y = (y - lmu) * lsc + lbe;
    gout[(size_t)bc * GPIT + idx] = 1.f / (1.f + expf(-y));

    a = idx > 0 ? y0b[idx - 1] : 0.f;
    b = y0b[idx];
    d = idx < NC - 1 ? y0b[idx + 1] : 0.f;
    y = hk0 * a + hk1 * b + hk2 * d;
    y = (y - hmu) * hsc + hbe;
    gout[(size_t)N_IMG * GPIT + (size_t)bc * GPIT + idx] = 1.f / (1.f + expf(-y));
  }
}

// =====================================================================
// Kernel 3: gating + column IDWT + row IDWT + residual.
// h16x8 staging loads, gates folded in, float4 outputs.
// =====================================================================
__global__ __launch_bounds__(512) void k_inv(const h16* __restrict__ wsh,
                                             const float* __restrict__ gbuf,
                                             const float* __restrict__ x,
                                             float* __restrict__ out) {
  __shared__ float sA[7][PITH], sB[7][PITH], sC[7][PITH], sD[7][PITH];
  __shared__ float a2[8][PITH], d2[8][PITH];
  __shared__ float sghl[PITH];
  const int bc = blockIdx.y;
  const int t0 = blockIdx.x * 8;
  const int u0 = t0 >> 1;
  const int tid = threadIdx.x;
  const h16* LLh = wsh            + (size_t)bc * S_IMGH;
  const h16* LHh = wsh +     NSB  + (size_t)bc * S_IMGH;
  const h16* HLh = wsh + 2 * NSB  + (size_t)bc * S_IMGH;
  const h16* HHh = wsh + 3 * NSB  + (size_t)bc * S_IMGH;
  const float* glh = gbuf + (size_t)bc * GPIT;
  const float* ghl = gbuf + (size_t)N_IMG * GPIT + (size_t)bc * GPIT;

  if (tid < 66) *(float4*)(sghl + 4 * tid) = *(const float4*)(ghl + 4 * tid);

  // stage 7 rows x 4 subbands; h16x8 loads, float4 LDS writes
  for (int q = tid; q < 7 * 33; q += 512) {
    const int j = q / 33, b8 = (q - j * 33) * 8;
    const int u = u0 + j;
    const float gl = glh[u];
    const size_t rb = (size_t)u * PITH + b8;
    const h16x8 A = *(const h16x8*)(LLh + rb);
    const h16x8 Bv = *(const h16x8*)(LHh + rb);
    const h16x8 Cv = *(const h16x8*)(HLh + rb);
    const h16x8 Dv = *(const h16x8*)(HHh + rb);
    float4 f0, f1;
    f0 = {(float)A[0], (float)A[1], (float)A[2], (float)A[3]};
    f1 = {(float)A[4], (float)A[5], (float)A[6], (float)A[7]};
    *(float4*)(&sA[j][b8]) = f0; *(float4*)(&sA[j][b8 + 4]) = f1;
    f0 = {(float)Bv[0] * gl, (float)Bv[1] * gl, (float)Bv[2] * gl, (float)Bv[3] * gl};
    f1 = {(float)Bv[4] * gl, (float)Bv[5] * gl, (float)Bv[6] * gl, (float)Bv[7] * gl};
    *(float4*)(&sB[j][b8]) = f0; *(float4*)(&sB[j][b8 + 4]) = f1;
    f0 = {(float)Cv[0], (float)Cv[1], (float)Cv[2], (float)Cv[3]};
    f1 = {(float)Cv[4], (float)Cv[5], (float)Cv[6], (float)Cv[7]};
    *(float4*)(&sC[j][b8]) = f0; *(float4*)(&sC[j][b8 + 4]) = f1;
    f0 = {(float)Dv[0], (float)Dv[1], (float)Dv[2], (float)Dv[3]};
    f1 = {(float)Dv[4], (float)Dv[5], (float)Dv[6], (float)Dv[7]};
    *(float4*)(&sD[j][b8]) = f0; *(float4*)(&sD[j][b8 + 4]) = f1;
  }
  __syncthreads();

  // column IDWT (2-col pairs); ghl gate folded into the HL partial
  for (int task = tid; task < 8 * 130; task += 512) {
    const int dt = task / 130, p = task - dt * 130;
    const int i = 2 * p;
    const int par = dt & 1, lj0 = dt >> 1;
    float avx = 0.f, avy = 0.f, dlx = 0.f, dly = 0.f, dhx = 0.f, dhy = 0.f;
#pragma unroll
    for (int jj = 0; jj < 4; ++jj) {
      const int lj = lj0 + 3 - jj;
      const float rl = par ? RLO[1 + 2 * jj] : RLO[2 * jj];
      const float rh = par ? RHI[1 + 2 * jj] : RHI[2 * jj];
      const float2 a_ = *(const float2*)(&sA[lj][i]);
      const float2 b_ = *(const float2*)(&sB[lj][i]);
      const float2 c_ = *(const float2*)(&sC[lj][i]);
      const float2 d_ = *(const float2*)(&sD[lj][i]);
      avx += a_.x * rl + b_.x * rh; avy += a_.y * rl + b_.y * rh;
      dlx += c_.x * rl;             dly += c_.y * rl;
      dhx += d_.x * rh;             dhy += d_.y * rh;
    }
    float2 o1, o2;
    o1.x = avx; o1.y = avy;
    o2.x = sghl[i] * dlx + dhx; o2.y = sghl[i + 1] * dly + dhy;
    *(float2*)(&a2[dt][i]) = o1;
    *(float2*)(&d2[dt][i]) = o2;
  }
  __syncthreads();

  // row IDWT + residual; each task -> 4 output cols (float4)
  for (int task = tid; task < 8 * 128; task += 512) {
    const int dt = task >> 7, r = task & 127;
    const int q = 2 * r;
    const float2 aq0 = *(const float2*)(&a2[dt][q]);
    const float2 aq1 = *(const float2*)(&a2[dt][q + 2]);
    const float a4 = a2[dt][q + 4];
    const float2 dq0 = *(const float2*)(&d2[dt][q]);
    const float2 dq1 = *(const float2*)(&d2[dt][q + 2]);
    const float d4 = d2[dt][q + 4];
    const float a_[5] = {aq0.x, aq0.y, aq1.x, aq1.y, a4};
    const float d_[5] = {dq0.x, dq0.y, dq1.x, dq1.y, d4};
    float v[4];
#pragma unroll
    for (int k = 0; k < 4; ++k) {
      float s = 0.f;
      const int base = k >> 1, par = k & 1;
#pragma unroll
      for (int jj = 0; jj < 4; ++jj) {
        s += a_[base + 3 - jj] * RLO[par + 2 * jj] + d_[base + 3 - jj] * RHI[par + 2 * jj];
      }
      v[k] = s;
    }
    const size_t orow = ((size_t)bc * H_IN + (size_t)(t0 + dt)) * W_IN + 4 * r;
    const float4 xv = *(const float4*)(x + orow);
    float4 ov;
    ov.x = xv.x + v[0]; ov.y = xv.y + v[1]; ov.z = xv.z + v[2]; ov.w = xv.w + v[3];
    *(float4*)(out + orow) = ov;
  }
}

extern "C" void kernel_launch(void* const* d_in, const int* in_sizes, int n_in,
                              void* d_out, int out_size, void* d_ws, size_t ws_size,
                              hipStream_t stream) {
  const float* x = (const float*)d_in[0];
  h16* wsh = (h16*)d_ws;
  float* gbuf = (float*)(wsh + 4 * NSB);
  float* out = (float*)d_out;

  k_fwd<<<dim3(33, N_IMG), 512, 0, stream>>>(x, wsh);
  k_gate<<<dim3(N_IMG), 512, 0, stream>>>(
      wsh, gbuf,
      (const float*)d_in[1], (const float*)d_in[2], (const float*)d_in[3],
      (const float*)d_in[4], (const float*)d_in[5], (const float*)d_in[6], (const float*)d_in[7],
      (const float*)d_in[8], (const float*)d_in[9], (const float*)d_in[10],
      (const float*)d_in[11], (const float*)d_in[12], (const float*)d_in[13], (const float*)d_in[14]);
  k_inv<<<dim3(64, N_IMG), 512, 0, stream>>>(wsh, gbuf, x, out);
}

// Round 4
// 450.007 us; speedup vs baseline: 4.5359x; 1.4435x over previous
//
#include <hip/hip_runtime.h>

typedef _Float16 h16;
typedef _Float16 h16x4 __attribute__((ext_vector_type(4)));
typedef _Float16 h16x8 __attribute__((ext_vector_type(8)));

// ---- problem constants ----
#define N_IMG 512      // B*C = 8*64
#define C_CH  64
#define H_IN  512
#define W_IN  512
#define NC    259      // subband extent: (512+8-1)//2
#define PIT   260      // f32 LDS pitch (k_fwd)
#define PITH  264      // fp16 subband row pitch (rows 16B-aligned)
#define S_IMGH ((size_t)NC * PITH)
#define NSB    ((size_t)N_IMG * S_IMGH)
#define GPIT  264
#define NSTRIP 33

constexpr float DLO[8] = {
  -0.010597401784997278f,  0.032883011666982945f,  0.030841381835986965f, -0.18703481171888114f,
  -0.02798376941698385f,   0.6308807679295904f,    0.7148465705525415f,    0.23037781330885523f};
constexpr float DHI[8] = {
  -0.23037781330885523f,   0.7148465705525415f,   -0.6308807679295904f,   -0.02798376941698385f,
   0.18703481171888114f,   0.030841381835986965f, -0.032883011666982945f, -0.010597401784997278f};
constexpr float RLO[8] = {
   0.23037781330885523f,   0.7148465705525415f,    0.6308807679295904f,   -0.02798376941698385f,
  -0.18703481171888114f,   0.030841381835986965f,  0.032883011666982945f, -0.010597401784997278f};
constexpr float RHI[8] = {
  -0.010597401784997278f, -0.032883011666982945f,  0.030841381835986965f,  0.18703481171888114f,
  -0.02798376941698385f,  -0.6308807679295904f,    0.7148465705525415f,   -0.23037781330885523f};

// =====================================================================
// Kernel 1: row DWT + column DWT -> LH, HL (fp16) only, plus fused gate
// statistics: complete LH row max/sum per strip row, HL column partials
// per strip. No LL/HH (perfect-reconstruction identity makes them moot).
// =====================================================================
__global__ __launch_bounds__(512) void k_fwd(const float* __restrict__ x,
                                             h16* __restrict__ wsh,
                                             float* __restrict__ stat) {
  __shared__ float sa[22 * PIT];
  __shared__ float sd[22 * PIT];
  const int bc = blockIdx.y;
  const int bx = blockIdx.x;
  const int h0 = bx * 8;
  const int hcount = min(8, NC - h0);
  const int nrows = 2 * hcount + 6;
  const int tid = threadIdx.x;
  const int wave = tid >> 6, lane = tid & 63;
  const float* xim = x + (size_t)bc * (H_IN * (size_t)W_IN);

  // Phase A: row DWT into LDS; boundaries from registers (no scalar loads)
  for (int j = wave; j < nrows; j += 8) {
    int r = 2 * h0 - 6 + j;
    r = r < 0 ? -r - 1 : (r >= H_IN ? 2 * H_IN - 1 - r : r);
    const float* xrow = xim + (size_t)r * W_IN;
    float* saj = sa + j * PIT;
    float* sdj = sd + j * PIT;
    const int base = lane ? 8 * lane - 8 : 0;
    const float4 q0 = *(const float4*)(xrow + base);
    const float4 q1 = *(const float4*)(xrow + base + 4);
    const float4 q2 = *(const float4*)(xrow + base + 8);
    const float4 q3 = *(const float4*)(xrow + base + 12);
    const float v[16] = {q0.x, q0.y, q0.z, q0.w, q1.x, q1.y, q1.z, q1.w,
                         q2.x, q2.y, q2.z, q2.w, q3.x, q3.y, q3.z, q3.w};
    float A[4], D[4];
    if (lane == 0) {
      // cols 0..3 from v[idx]=x[idx], reflected left taps (constants)
#pragma unroll
      for (int i = 0; i < 4; ++i) {
        float a = 0.f, d = 0.f;
#pragma unroll
        for (int m = 0; m < 8; ++m) {
          int p = 2 * i + 1 - m; p = p < 0 ? -p - 1 : p;
          const float t = v[p];
          a += DLO[m] * t; d += DHI[m] * t;
        }
        A[i] = a; D[i] = d;
      }
      *(float4*)(saj) = {A[0], A[1], A[2], A[3]};
      *(float4*)(sdj) = {D[0], D[1], D[2], D[3]};
    } else {
#pragma unroll
      for (int k = 0; k < 4; ++k) {
        float a = 0.f, d = 0.f;
#pragma unroll
        for (int m = 0; m < 8; ++m) {
          const float t = v[2 * k + 9 - m];
          a += DLO[m] * t; d += DHI[m] * t;
        }
        A[k] = a; D[k] = d;
      }
      *(float4*)(saj + 4 * lane) = {A[0], A[1], A[2], A[3]};
      *(float4*)(sdj + 4 * lane) = {D[0], D[1], D[2], D[3]};
      if (lane == 63) {
        // cols 256..258 from v[idx]=x[496+idx], reflected right taps
#pragma unroll
        for (int i = 256; i < 259; ++i) {
          float a = 0.f, d = 0.f;
#pragma unroll
          for (int m = 0; m < 8; ++m) {
            int p = 2 * i + 1 - m; p = p >= 512 ? 1023 - p : p;
            const float t = v[p - 496];
            a += DLO[m] * t; d += DHI[m] * t;
          }
          saj[i] = a; sdj[i] = d;
        }
      }
    }
  }
  __syncthreads();

  // Phase B: column DWT -> LH (DHI over A) and HL (DLO over D)
  h16* __restrict__ LHp = wsh;
  h16* __restrict__ HLp = wsh + NSB;
  const size_t obase = (size_t)bc * S_IMGH;
  const int ntask = hcount * 65;
  float rlh[2][4], rhl[2][4];
#pragma unroll
  for (int slot = 0; slot < 2; ++slot) {
    const int task = tid + slot * 512;
    if (task < ntask) {
      const int dh = task / 65, p = task - dh * 65;
      const int i0 = 4 * p;
      float lh[4] = {0, 0, 0, 0}, hl[4] = {0, 0, 0, 0};
#pragma unroll
      for (int m = 0; m < 8; ++m) {
        const int j = 2 * dh + 7 - m;
        const float4 av = *(const float4*)(sa + j * PIT + i0);
        const float4 dv = *(const float4*)(sd + j * PIT + i0);
        lh[0] += DHI[m] * av.x; lh[1] += DHI[m] * av.y; lh[2] += DHI[m] * av.z; lh[3] += DHI[m] * av.w;
        hl[0] += DLO[m] * dv.x; hl[1] += DLO[m] * dv.y; hl[2] += DLO[m] * dv.z; hl[3] += DLO[m] * dv.w;
      }
      if (i0 == 256) { lh[3] = 0.f; hl[3] = 0.f; }   // pad col 259 = 0
      const size_t ob = obase + (size_t)(h0 + dh) * PITH + i0;
      h16x4 o;
      o[0] = (h16)lh[0]; o[1] = (h16)lh[1]; o[2] = (h16)lh[2]; o[3] = (h16)lh[3];
      *(h16x4*)(LHp + ob) = o;
      o[0] = (h16)hl[0]; o[1] = (h16)hl[1]; o[2] = (h16)hl[2]; o[3] = (h16)hl[3];
      *(h16x4*)(HLp + ob) = o;
#pragma unroll
      for (int k = 0; k < 4; ++k) { rlh[slot][k] = lh[k]; rhl[slot][k] = hl[k]; }
    }
  }
  __syncthreads();

  // Phase C: gate stats. Reuse sa region as scratch.
  float* scol = sa;                 // [8][264] HL values
  float* prmx = sa + 8 * 264;       // [520] per-task LH max
  float* prsm = prmx + 520;         // [520] per-task LH sum
#pragma unroll
  for (int slot = 0; slot < 2; ++slot) {
    const int task = tid + slot * 512;
    if (task < ntask) {
      const int dh = task / 65, p = task - dh * 65;
      *(float4*)(scol + dh * 264 + 4 * p) = {rhl[slot][0], rhl[slot][1], rhl[slot][2], rhl[slot][3]};
      const float m01 = fmaxf(rlh[slot][0], rlh[slot][1]);
      const float m23 = (p == 64) ? rlh[slot][2] : fmaxf(rlh[slot][2], rlh[slot][3]);
      prmx[task] = fmaxf(m01, m23);
      prsm[task] = rlh[slot][0] + rlh[slot][1] + rlh[slot][2] + rlh[slot][3];
    }
  }
  __syncthreads();
  float* rsM = stat;                                    // [512*264]
  float* rsS = stat + (size_t)N_IMG * 264;
  float* cpM = rsS + (size_t)N_IMG * 264;               // [512*33*264]
  float* cpS = cpM + (size_t)N_IMG * NSTRIP * 264;
  if (wave < hcount) {
    float m = prmx[wave * 65 + lane], s = prsm[wave * 65 + lane];
    if (lane == 0) { m = fmaxf(m, prmx[wave * 65 + 64]); s += prsm[wave * 65 + 64]; }
#pragma unroll
    for (int off = 32; off; off >>= 1) {
      m = fmaxf(m, __shfl_xor(m, off)); s += __shfl_xor(s, off);
    }
    if (lane == 0) {
      rsM[bc * 264 + h0 + wave] = m;
      rsS[bc * 264 + h0 + wave] = s;
    }
  }
  if (tid < 264) {
    float m = -3.4e38f, s = 0.f;
    for (int dh = 0; dh < hcount; ++dh) {
      const float vv = scol[dh * 264 + tid]; m = fmaxf(m, vv); s += vv;
    }
    const size_t cb = ((size_t)bc * NSTRIP + bx) * 264 + tid;
    cpM[cb] = m; cpS[cb] = s;
  }
}

// =====================================================================
// Kernel 2: finish gates from stats only. Writes (sigmoid(y) - 1).
// =====================================================================
__global__ __launch_bounds__(256) void k_gate(
    const float* __restrict__ stat, float* __restrict__ gout,
    const float* lc1w, const float* lc1b, const float* lc2w,
    const float* lg, const float* lb, const float* lm, const float* lv,
    const float* hc1w, const float* hc1b, const float* hc2w,
    const float* hg, const float* hb, const float* hm, const float* hv) {
  __shared__ float cmx[264], csm[264], y0a[264], y0b[264];
  const int bc = blockIdx.x;
  const int tid = threadIdx.x;
  const float* rsM = stat;
  const float* rsS = stat + (size_t)N_IMG * 264;
  const float* cpM = rsS + (size_t)N_IMG * 264;
  const float* cpS = cpM + (size_t)N_IMG * NSTRIP * 264;

  for (int col = tid; col < 264; col += 256) {
    float m = -3.4e38f, s = 0.f;
    for (int st = 0; st < NSTRIP; ++st) {
      const size_t cb = ((size_t)bc * NSTRIP + st) * 264 + col;
      m = fmaxf(m, cpM[cb]); s += cpS[cb];
    }
    cmx[col] = m; csm[col] = s;
  }
  __syncthreads();
  const float lw0 = lc1w[0], lw1 = lc1w[1], lbb0 = lc1b[0];
  const float hw0 = hc1w[0], hw1 = hc1w[1], hbb0 = hc1b[0];
  for (int idx = tid; idx < NC; idx += 256) {
    y0a[idx] = lw0 * rsM[bc * 264 + idx] + lw1 * (rsS[bc * 264 + idx] * (1.f / NC)) + lbb0;
    y0b[idx] = hw0 * cmx[idx] + hw1 * (csm[idx] * (1.f / NC)) + hbb0;
  }
  __syncthreads();
  const int c = bc & (C_CH - 1);
  const float lk0 = lc2w[c * 3], lk1 = lc2w[c * 3 + 1], lk2 = lc2w[c * 3 + 2];
  const float hk0 = hc2w[c * 3], hk1 = hc2w[c * 3 + 1], hk2 = hc2w[c * 3 + 2];
  const float lsc = rsqrtf(lv[c] + 1e-5f) * lg[c], lmu = lm[c], lbe = lb[c];
  const float hsc = rsqrtf(hv[c] + 1e-5f) * hg[c], hmu = hm[c], hbe = hb[c];
  for (int idx = tid; idx < NC; idx += 256) {
    float a = idx > 0 ? y0a[idx - 1] : 0.f;
    float b = y0a[idx];
    float d = idx < NC - 1 ? y0a[idx + 1] : 0.f;
    float y = lk0 * a + lk1 * b + lk2 * d;
    y = (y - lmu) * lsc + lbe;
    gout[(size_t)bc * GPIT + idx] = 1.f / (1.f + expf(-y)) - 1.f;

    a = idx > 0 ? y0b[idx - 1] : 0.f;
    b = y0b[idx];
    d = idx < NC - 1 ? y0b[idx + 1] : 0.f;
    y = hk0 * a + hk1 * b + hk2 * d;
    y = (y - hmu) * hsc + hbe;
    gout[(size_t)N_IMG * GPIT + (size_t)bc * GPIT + idx] = 1.f / (1.f + expf(-y)) - 1.f;
  }
}

// =====================================================================
// Kernel 3: out = 2x + IDWT(0, (g-1)LH, (g'-1)HL, 0).
// =====================================================================
__global__ __launch_bounds__(512) void k_inv(const h16* __restrict__ wsh,
                                             const float* __restrict__ gbuf,
                                             const float* __restrict__ x,
                                             float* __restrict__ out) {
  __shared__ float sB[7][PITH], sC[7][PITH];
  __shared__ float a2[8][PITH], d2[8][PITH];
  __shared__ float sghl[PITH];
  const int bc = blockIdx.y;
  const int t0 = blockIdx.x * 8;
  const int u0 = t0 >> 1;
  const int tid = threadIdx.x;
  const h16* LHh = wsh       + (size_t)bc * S_IMGH;
  const h16* HLh = wsh + NSB + (size_t)bc * S_IMGH;
  const float* glh = gbuf + (size_t)bc * GPIT;
  const float* ghl = gbuf + (size_t)N_IMG * GPIT + (size_t)bc * GPIT;

  if (tid < 66) *(float4*)(sghl + 4 * tid) = *(const float4*)(ghl + 4 * tid);

  // stage 7 rows of LH*(g-1) and raw HL
  for (int q = tid; q < 7 * 33; q += 512) {
    const int j = q / 33, b8 = (q - j * 33) * 8;
    const int u = u0 + j;
    const float gl = glh[u];                    // (g - 1)
    const size_t rb = (size_t)u * PITH + b8;
    const h16x8 Bv = *(const h16x8*)(LHh + rb);
    const h16x8 Cv = *(const h16x8*)(HLh + rb);
    float4 f0 = {(float)Bv[0] * gl, (float)Bv[1] * gl, (float)Bv[2] * gl, (float)Bv[3] * gl};
    float4 f1 = {(float)Bv[4] * gl, (float)Bv[5] * gl, (float)Bv[6] * gl, (float)Bv[7] * gl};
    *(float4*)(&sB[j][b8]) = f0; *(float4*)(&sB[j][b8 + 4]) = f1;
    f0 = {(float)Cv[0], (float)Cv[1], (float)Cv[2], (float)Cv[3]};
    f1 = {(float)Cv[4], (float)Cv[5], (float)Cv[6], (float)Cv[7]};
    *(float4*)(&sC[j][b8]) = f0; *(float4*)(&sC[j][b8 + 4]) = f1;
  }
  __syncthreads();

  // column IDWT halves: a2 = RHI ⊗ sB ; d2 = (g'-1) * (RLO ⊗ sC)
  for (int task = tid; task < 8 * 132; task += 512) {
    const int dt = task / 132, p = task - dt * 132;
    const int i = 2 * p;
    const int par = dt & 1, lj0 = dt >> 1;
    float ax = 0.f, ay = 0.f, dx_ = 0.f, dy_ = 0.f;
#pragma unroll
    for (int jj = 0; jj < 4; ++jj) {
      const int lj = lj0 + 3 - jj;
      const float rh = par ? RHI[1 + 2 * jj] : RHI[2 * jj];
      const float rl = par ? RLO[1 + 2 * jj] : RLO[2 * jj];
      const float2 b_ = *(const float2*)(&sB[lj][i]);
      const float2 c_ = *(const float2*)(&sC[lj][i]);
      ax += b_.x * rh; ay += b_.y * rh;
      dx_ += c_.x * rl; dy_ += c_.y * rl;
    }
    *(float2*)(&a2[dt][i]) = {ax, ay};
    *(float2*)(&d2[dt][i]) = {sghl[i] * dx_, sghl[i + 1] * dy_};
  }
  __syncthreads();

  // row IDWT + out = 2x + corr
  for (int task = tid; task < 8 * 128; task += 512) {
    const int dt = task >> 7, r = task & 127;
    const int q = 2 * r;
    const float a_[5] = {a2[dt][q], a2[dt][q + 1], a2[dt][q + 2], a2[dt][q + 3], a2[dt][q + 4]};
    const float d_[5] = {d2[dt][q], d2[dt][q + 1], d2[dt][q + 2], d2[dt][q + 3], d2[dt][q + 4]};
    float vv[4];
#pragma unroll
    for (int k = 0; k < 4; ++k) {
      float s = 0.f;
      const int base = k >> 1, par = k & 1;
#pragma unroll
      for (int jj = 0; jj < 4; ++jj)
        s += a_[base + 3 - jj] * RLO[par + 2 * jj] + d_[base + 3 - jj] * RHI[par + 2 * jj];
      vv[k] = s;
    }
    const size_t orow = ((size_t)bc * H_IN + (size_t)(t0 + dt)) * W_IN + 4 * r;
    const float4 xv = *(const float4*)(x + orow);
    *(float4*)(out + orow) = {2.f * xv.x + vv[0], 2.f * xv.y + vv[1],
                              2.f * xv.z + vv[2], 2.f * xv.w + vv[3]};
  }
}

extern "C" void kernel_launch(void* const* d_in, const int* in_sizes, int n_in,
                              void* d_out, int out_size, void* d_ws, size_t ws_size,
                              hipStream_t stream) {
  const float* x = (const float*)d_in[0];
  h16* wsh = (h16*)d_ws;
  float* statf = (float*)(wsh + 2 * NSB);
  // stat layout: rsM[512*264] | rsS | cpM[512*33*264] | cpS | glh[512*264] | ghl[512*264]
  float* gbuf = statf + 2 * (size_t)N_IMG * 264 + 2 * (size_t)N_IMG * NSTRIP * 264;
  float* out = (float*)d_out;

  k_fwd<<<dim3(NSTRIP, N_IMG), 512, 0, stream>>>(x, wsh, statf);
  k_gate<<<dim3(N_IMG), 256, 0, stream>>>(
      statf, gbuf,
      (const float*)d_in[1], (const float*)d_in[2], (const float*)d_in[3],
      (const float*)d_in[4], (const float*)d_in[5], (const float*)d_in[6], (const float*)d_in[7],
      (const float*)d_in[8], (const float*)d_in[9], (const float*)d_in[10],
      (const float*)d_in[11], (const float*)d_in[12], (const float*)d_in[13], (const float*)d_in[14]);
  k_inv<<<dim3(64, N_IMG), 512, 0, stream>>>(wsh, gbuf, x, out);
}

// Round 6
// 437.586 us; speedup vs baseline: 4.6647x; 1.0284x over previous
//
#include <hip/hip_runtime.h>

typedef _Float16 h16;
typedef _Float16 h16x4 __attribute__((ext_vector_type(4)));
typedef _Float16 h16x8 __attribute__((ext_vector_type(8)));
typedef float f32x4 __attribute__((ext_vector_type(4)));

// ---- problem constants ----
#define N_IMG 512      // B*C = 8*64
#define C_CH  64
#define H_IN  512
#define W_IN  512
#define NC    259      // subband extent: (512+8-1)//2
#define PIT   260      // f32 LDS pitch (k_fwd)
#define PITH  264      // fp16 subband row pitch (rows 16B-aligned)
#define S_IMGH ((size_t)NC * PITH)
#define NSB    ((size_t)N_IMG * S_IMGH)
#define GPIT  264
#define NSTRIP 33

constexpr float DLO[8] = {
  -0.010597401784997278f,  0.032883011666982945f,  0.030841381835986965f, -0.18703481171888114f,
  -0.02798376941698385f,   0.6308807679295904f,    0.7148465705525415f,    0.23037781330885523f};
constexpr float DHI[8] = {
  -0.23037781330885523f,   0.7148465705525415f,   -0.6308807679295904f,   -0.02798376941698385f,
   0.18703481171888114f,   0.030841381835986965f, -0.032883011666982945f, -0.010597401784997278f};
constexpr float RLO[8] = {
   0.23037781330885523f,   0.7148465705525415f,    0.6308807679295904f,   -0.02798376941698385f,
  -0.18703481171888114f,   0.030841381835986965f,  0.032883011666982945f, -0.010597401784997278f};
constexpr float RHI[8] = {
  -0.010597401784997278f, -0.032883011666982945f,  0.030841381835986965f,  0.18703481171888114f,
  -0.02798376941698385f,  -0.6308807679295904f,    0.7148465705525415f,   -0.23037781330885523f};

// =====================================================================
// Kernel 1: row DWT + column DWT -> LH, HL (fp16) only, plus fused gate
// statistics. 1-D grid with XCD-chunk swizzle: each XCD gets contiguous
// (image, strip) work so strip halos hit its L2.
// =====================================================================
__global__ __launch_bounds__(512) void k_fwd(const float* __restrict__ x,
                                             h16* __restrict__ wsh,
                                             float* __restrict__ stat) {
  __shared__ float sa[22 * PIT];
  __shared__ float sd[22 * PIT];
  // bijective XCD swizzle: nwg = 16896 = 8 * 2112
  const int p = blockIdx.x;
  const int w = (p & 7) * 2112 + (p >> 3);
  const int bc = w / NSTRIP;
  const int bx = w - bc * NSTRIP;
  const int h0 = bx * 8;
  const int hcount = min(8, NC - h0);
  const int nrows = 2 * hcount + 6;
  const int tid = threadIdx.x;
  const int wave = tid >> 6, lane = tid & 63;
  const float* xim = x + (size_t)bc * (H_IN * (size_t)W_IN);

  // Phase A: row DWT into LDS; boundaries from registers (no scalar loads)
  for (int j = wave; j < nrows; j += 8) {
    int r = 2 * h0 - 6 + j;
    r = r < 0 ? -r - 1 : (r >= H_IN ? 2 * H_IN - 1 - r : r);
    const float* xrow = xim + (size_t)r * W_IN;
    float* saj = sa + j * PIT;
    float* sdj = sd + j * PIT;
    const int base = lane ? 8 * lane - 8 : 0;
    const float4 q0 = *(const float4*)(xrow + base);
    const float4 q1 = *(const float4*)(xrow + base + 4);
    const float4 q2 = *(const float4*)(xrow + base + 8);
    const float4 q3 = *(const float4*)(xrow + base + 12);
    const float v[16] = {q0.x, q0.y, q0.z, q0.w, q1.x, q1.y, q1.z, q1.w,
                         q2.x, q2.y, q2.z, q2.w, q3.x, q3.y, q3.z, q3.w};
    float A[4], D[4];
    if (lane == 0) {
#pragma unroll
      for (int i = 0; i < 4; ++i) {
        float a = 0.f, d = 0.f;
#pragma unroll
        for (int m = 0; m < 8; ++m) {
          int pp = 2 * i + 1 - m; pp = pp < 0 ? -pp - 1 : pp;
          const float t = v[pp];
          a += DLO[m] * t; d += DHI[m] * t;
        }
        A[i] = a; D[i] = d;
      }
      *(float4*)(saj) = {A[0], A[1], A[2], A[3]};
      *(float4*)(sdj) = {D[0], D[1], D[2], D[3]};
    } else {
#pragma unroll
      for (int k = 0; k < 4; ++k) {
        float a = 0.f, d = 0.f;
#pragma unroll
        for (int m = 0; m < 8; ++m) {
          const float t = v[2 * k + 9 - m];
          a += DLO[m] * t; d += DHI[m] * t;
        }
        A[k] = a; D[k] = d;
      }
      *(float4*)(saj + 4 * lane) = {A[0], A[1], A[2], A[3]};
      *(float4*)(sdj + 4 * lane) = {D[0], D[1], D[2], D[3]};
      if (lane == 63) {
#pragma unroll
        for (int i = 256; i < 259; ++i) {
          float a = 0.f, d = 0.f;
#pragma unroll
          for (int m = 0; m < 8; ++m) {
            int pp = 2 * i + 1 - m; pp = pp >= 512 ? 1023 - pp : pp;
            const float t = v[pp - 496];
            a += DLO[m] * t; d += DHI[m] * t;
          }
          saj[i] = a; sdj[i] = d;
        }
      }
    }
  }
  __syncthreads();

  // Phase B: column DWT -> LH (DHI over A) and HL (DLO over D)
  h16* __restrict__ LHp = wsh;
  h16* __restrict__ HLp = wsh + NSB;
  const size_t obase = (size_t)bc * S_IMGH;
  const int ntask = hcount * 65;
  float rlh[2][4], rhl[2][4];
#pragma unroll
  for (int slot = 0; slot < 2; ++slot) {
    const int task = tid + slot * 512;
    if (task < ntask) {
      const int dh = task / 65, pq = task - dh * 65;
      const int i0 = 4 * pq;
      float lh[4] = {0, 0, 0, 0}, hl[4] = {0, 0, 0, 0};
#pragma unroll
      for (int m = 0; m < 8; ++m) {
        const int j = 2 * dh + 7 - m;
        const float4 av = *(const float4*)(sa + j * PIT + i0);
        const float4 dv = *(const float4*)(sd + j * PIT + i0);
        lh[0] += DHI[m] * av.x; lh[1] += DHI[m] * av.y; lh[2] += DHI[m] * av.z; lh[3] += DHI[m] * av.w;
        hl[0] += DLO[m] * dv.x; hl[1] += DLO[m] * dv.y; hl[2] += DLO[m] * dv.z; hl[3] += DLO[m] * dv.w;
      }
      if (i0 == 256) { lh[3] = 0.f; hl[3] = 0.f; }
      const size_t ob = obase + (size_t)(h0 + dh) * PITH + i0;
      h16x4 o;
      o[0] = (h16)lh[0]; o[1] = (h16)lh[1]; o[2] = (h16)lh[2]; o[3] = (h16)lh[3];
      *(h16x4*)(LHp + ob) = o;
      o[0] = (h16)hl[0]; o[1] = (h16)hl[1]; o[2] = (h16)hl[2]; o[3] = (h16)hl[3];
      *(h16x4*)(HLp + ob) = o;
#pragma unroll
      for (int k = 0; k < 4; ++k) { rlh[slot][k] = lh[k]; rhl[slot][k] = hl[k]; }
    }
  }
  __syncthreads();

  // Phase C: gate stats. Reuse sa region as scratch.
  float* scol = sa;
  float* prmx = sa + 8 * 264;
  float* prsm = prmx + 520;
#pragma unroll
  for (int slot = 0; slot < 2; ++slot) {
    const int task = tid + slot * 512;
    if (task < ntask) {
      const int dh = task / 65, pq = task - dh * 65;
      *(float4*)(scol + dh * 264 + 4 * pq) = {rhl[slot][0], rhl[slot][1], rhl[slot][2], rhl[slot][3]};
      const float m01 = fmaxf(rlh[slot][0], rlh[slot][1]);
      const float m23 = (pq == 64) ? rlh[slot][2] : fmaxf(rlh[slot][2], rlh[slot][3]);
      prmx[task] = fmaxf(m01, m23);
      prsm[task] = rlh[slot][0] + rlh[slot][1] + rlh[slot][2] + rlh[slot][3];
    }
  }
  __syncthreads();
  float* rsM = stat;
  float* rsS = stat + (size_t)N_IMG * 264;
  float* cpM = rsS + (size_t)N_IMG * 264;
  float* cpS = cpM + (size_t)N_IMG * NSTRIP * 264;
  if (wave < hcount) {
    float m = prmx[wave * 65 + lane], s = prsm[wave * 65 + lane];
    if (lane == 0) { m = fmaxf(m, prmx[wave * 65 + 64]); s += prsm[wave * 65 + 64]; }
#pragma unroll
    for (int off = 32; off; off >>= 1) {
      m = fmaxf(m, __shfl_xor(m, off)); s += __shfl_xor(s, off);
    }
    if (lane == 0) {
      rsM[bc * 264 + h0 + wave] = m;
      rsS[bc * 264 + h0 + wave] = s;
    }
  }
  if (tid < 264) {
    float m = -3.4e38f, s = 0.f;
    for (int dh = 0; dh < hcount; ++dh) {
      const float vv = scol[dh * 264 + tid]; m = fmaxf(m, vv); s += vv;
    }
    const size_t cb = ((size_t)bc * NSTRIP + bx) * 264 + tid;
    cpM[cb] = m; cpS[cb] = s;
  }
}

// =====================================================================
// Kernel 2: finish gates from stats only. Writes (sigmoid(y) - 1).
// =====================================================================
__global__ __launch_bounds__(256) void k_gate(
    const float* __restrict__ stat, float* __restrict__ gout,
    const float* lc1w, const float* lc1b, const float* lc2w,
    const float* lg, const float* lb, const float* lm, const float* lv,
    const float* hc1w, const float* hc1b, const float* hc2w,
    const float* hg, const float* hb, const float* hm, const float* hv) {
  __shared__ float cmx[264], csm[264], y0a[264], y0b[264];
  const int bc = blockIdx.x;
  const int tid = threadIdx.x;
  const float* rsM = stat;
  const float* rsS = stat + (size_t)N_IMG * 264;
  const float* cpM = rsS + (size_t)N_IMG * 264;
  const float* cpS = cpM + (size_t)N_IMG * NSTRIP * 264;

  for (int col = tid; col < 264; col += 256) {
    float m = -3.4e38f, s = 0.f;
    for (int st = 0; st < NSTRIP; ++st) {
      const size_t cb = ((size_t)bc * NSTRIP + st) * 264 + col;
      m = fmaxf(m, cpM[cb]); s += cpS[cb];
    }
    cmx[col] = m; csm[col] = s;
  }
  __syncthreads();
  const float lw0 = lc1w[0], lw1 = lc1w[1], lbb0 = lc1b[0];
  const float hw0 = hc1w[0], hw1 = hc1w[1], hbb0 = hc1b[0];
  for (int idx = tid; idx < NC; idx += 256) {
    y0a[idx] = lw0 * rsM[bc * 264 + idx] + lw1 * (rsS[bc * 264 + idx] * (1.f / NC)) + lbb0;
    y0b[idx] = hw0 * cmx[idx] + hw1 * (csm[idx] * (1.f / NC)) + hbb0;
  }
  __syncthreads();
  const int c = bc & (C_CH - 1);
  const float lk0 = lc2w[c * 3], lk1 = lc2w[c * 3 + 1], lk2 = lc2w[c * 3 + 2];
  const float hk0 = hc2w[c * 3], hk1 = hc2w[c * 3 + 1], hk2 = hc2w[c * 3 + 2];
  const float lsc = rsqrtf(lv[c] + 1e-5f) * lg[c], lmu = lm[c], lbe = lb[c];
  const float hsc = rsqrtf(hv[c] + 1e-5f) * hg[c], hmu = hm[c], hbe = hb[c];
  for (int idx = tid; idx < NC; idx += 256) {
    float a = idx > 0 ? y0a[idx - 1] : 0.f;
    float b = y0a[idx];
    float d = idx < NC - 1 ? y0a[idx + 1] : 0.f;
    float y = lk0 * a + lk1 * b + lk2 * d;
    y = (y - lmu) * lsc + lbe;
    gout[(size_t)bc * GPIT + idx] = 1.f / (1.f + expf(-y)) - 1.f;

    a = idx > 0 ? y0b[idx - 1] : 0.f;
    b = y0b[idx];
    d = idx < NC - 1 ? y0b[idx + 1] : 0.f;
    y = hk0 * a + hk1 * b + hk2 * d;
    y = (y - hmu) * hsc + hbe;
    gout[(size_t)N_IMG * GPIT + (size_t)bc * GPIT + idx] = 1.f / (1.f + expf(-y)) - 1.f;
  }
}

// =====================================================================
// Kernel 3: out = 2x + IDWT(0, (g-1)LH, (g'-1)HL, 0). XCD-chunk swizzle
// so strip-halo subband rows hit L2; nontemporal x/out streams.
// =====================================================================
__global__ __launch_bounds__(512) void k_inv(const h16* __restrict__ wsh,
                                             const float* __restrict__ gbuf,
                                             const float* __restrict__ x,
                                             float* __restrict__ out) {
  __shared__ float sB[7][PITH], sC[7][PITH];
  __shared__ float a2[8][PITH], d2[8][PITH];
  __shared__ float sghl[PITH];
  // bijective XCD swizzle: nwg = 32768 = 8 * 4096
  const int p = blockIdx.x;
  const int w = (p & 7) * 4096 + (p >> 3);
  const int bc = w >> 6;
  const int t0 = (w & 63) * 8;
  const int u0 = t0 >> 1;
  const int tid = threadIdx.x;
  const h16* LHh = wsh       + (size_t)bc * S_IMGH;
  const h16* HLh = wsh + NSB + (size_t)bc * S_IMGH;
  const float* glh = gbuf + (size_t)bc * GPIT;
  const float* ghl = gbuf + (size_t)N_IMG * GPIT + (size_t)bc * GPIT;

  if (tid < 66) *(float4*)(sghl + 4 * tid) = *(const float4*)(ghl + 4 * tid);

  // stage 7 rows of LH*(g-1) and raw HL
  for (int q = tid; q < 7 * 33; q += 512) {
    const int j = q / 33, b8 = (q - j * 33) * 8;
    const int u = u0 + j;
    const float gl = glh[u];                    // (g - 1)
    const size_t rb = (size_t)u * PITH + b8;
    const h16x8 Bv = *(const h16x8*)(LHh + rb);
    const h16x8 Cv = *(const h16x8*)(HLh + rb);
    float4 f0 = {(float)Bv[0] * gl, (float)Bv[1] * gl, (float)Bv[2] * gl, (float)Bv[3] * gl};
    float4 f1 = {(float)Bv[4] * gl, (float)Bv[5] * gl, (float)Bv[6] * gl, (float)Bv[7] * gl};
    *(float4*)(&sB[j][b8]) = f0; *(float4*)(&sB[j][b8 + 4]) = f1;
    f0 = {(float)Cv[0], (float)Cv[1], (float)Cv[2], (float)Cv[3]};
    f1 = {(float)Cv[4], (float)Cv[5], (float)Cv[6], (float)Cv[7]};
    *(float4*)(&sC[j][b8]) = f0; *(float4*)(&sC[j][b8 + 4]) = f1;
  }
  __syncthreads();

  // column IDWT halves: a2 = RHI ⊗ sB ; d2 = (g'-1) * (RLO ⊗ sC)
  for (int task = tid; task < 8 * 132; task += 512) {
    const int dt = task / 132, pq = task - dt * 132;
    const int i = 2 * pq;
    const int par = dt & 1, lj0 = dt >> 1;
    float ax = 0.f, ay = 0.f, dx_ = 0.f, dy_ = 0.f;
#pragma unroll
    for (int jj = 0; jj < 4; ++jj) {
      const int lj = lj0 + 3 - jj;
      const float rh = par ? RHI[1 + 2 * jj] : RHI[2 * jj];
      const float rl = par ? RLO[1 + 2 * jj] : RLO[2 * jj];
      const float2 b_ = *(const float2*)(&sB[lj][i]);
      const float2 c_ = *(const float2*)(&sC[lj][i]);
      ax += b_.x * rh; ay += b_.y * rh;
      dx_ += c_.x * rl; dy_ += c_.y * rl;
    }
    *(float2*)(&a2[dt][i]) = {ax, ay};
    *(float2*)(&d2[dt][i]) = {sghl[i] * dx_, sghl[i + 1] * dy_};
  }
  __syncthreads();

  // row IDWT + out = 2x + corr (nontemporal x/out)
  for (int task = tid; task < 8 * 128; task += 512) {
    const int dt = task >> 7, r = task & 127;
    const int q = 2 * r;
    const float a_[5] = {a2[dt][q], a2[dt][q + 1], a2[dt][q + 2], a2[dt][q + 3], a2[dt][q + 4]};
    const float d_[5] = {d2[dt][q], d2[dt][q + 1], d2[dt][q + 2], d2[dt][q + 3], d2[dt][q + 4]};
    float vv[4];
#pragma unroll
    for (int k = 0; k < 4; ++k) {
      float s = 0.f;
      const int base = k >> 1, par = k & 1;
#pragma unroll
      for (int jj = 0; jj < 4; ++jj)
        s += a_[base + 3 - jj] * RLO[par + 2 * jj] + d_[base + 3 - jj] * RHI[par + 2 * jj];
      vv[k] = s;
    }
    const size_t orow = ((size_t)bc * H_IN + (size_t)(t0 + dt)) * W_IN + 4 * r;
    const f32x4 xv = __builtin_nontemporal_load((const f32x4*)(x + orow));
    f32x4 ov;
    ov.x = 2.f * xv.x + vv[0]; ov.y = 2.f * xv.y + vv[1];
    ov.z = 2.f * xv.z + vv[2]; ov.w = 2.f * xv.w + vv[3];
    __builtin_nontemporal_store(ov, (f32x4*)(out + orow));
  }
}

extern "C" void kernel_launch(void* const* d_in, const int* in_sizes, int n_in,
                              void* d_out, int out_size, void* d_ws, size_t ws_size,
                              hipStream_t stream) {
  const float* x = (const float*)d_in[0];
  h16* wsh = (h16*)d_ws;
  float* statf = (float*)(wsh + 2 * NSB);
  float* gbuf = statf + 2 * (size_t)N_IMG * 264 + 2 * (size_t)N_IMG * NSTRIP * 264;
  float* out = (float*)d_out;

  k_fwd<<<dim3(NSTRIP * N_IMG), 512, 0, stream>>>(x, wsh, statf);
  k_gate<<<dim3(N_IMG), 256, 0, stream>>>(
      statf, gbuf,
      (const float*)d_in[1], (const float*)d_in[2], (const float*)d_in[3],
      (const float*)d_in[4], (const float*)d_in[5], (const float*)d_in[6], (const float*)d_in[7],
      (const float*)d_in[8], (const float*)d_in[9], (const float*)d_in[10],
      (const float*)d_in[11], (const float*)d_in[12], (const float*)d_in[13], (const float*)d_in[14]);
  k_inv<<<dim3(64 * N_IMG), 512, 0, stream>>>(wsh, gbuf, x, out);
}